// Round 13
// baseline (161.026 us; speedup 1.0000x reference)
//
#include <hip/hip_runtime.h>
#include <hip/hip_bf16.h>
#include <math.h>

#define BS   8192
#define DD   768
#define NC   64
#define NCL  500
#define CS   100
#define NY   1000
#define EPSN 1e-12f

typedef __attribute__((ext_vector_type(8))) short bf16x8;
typedef __attribute__((ext_vector_type(4))) float f32x4;

union B8 { unsigned u[4]; bf16x8 v; uint4 q; };

__device__ inline unsigned short f2bf(float x) {
    __hip_bfloat16 h = __float2bfloat16(x);
    return *reinterpret_cast<unsigned short*>(&h);
}
__device__ inline unsigned pk2(float a, float b) {
    return (unsigned)f2bf(a) | ((unsigned)f2bf(b) << 16);
}

#define FMA4(acc, s, v) { (acc).x = fmaf((s), (v).x, (acc).x); \
                          (acc).y = fmaf((s), (v).y, (acc).y); \
                          (acc).z = fmaf((s), (v).z, (acc).z); \
                          (acc).w = fmaf((s), (v).w, (acc).w); }

// ===== K1: tmat MFMA self-packing (128) || cmean partials (1500) ||
//           gram ksplit (256) || U (32)  — all mutually independent =====
__global__ __launch_bounds__(256) void k_front(
    const float* __restrict__ clusters, const float* __restrict__ C,
    const float* __restrict__ W, const float* __restrict__ X,
    float* __restrict__ cmP, float* __restrict__ gramP,
    float* __restrict__ Up, unsigned short* __restrict__ Tb) {
    __shared__ __align__(16) char smem_raw[25600];
    int b = blockIdx.x, tid = threadIdx.x;
    if (b < 128) {
        // T = X @ C via MFMA. R12 change: C granules self-packed into LDS per
        // 64-k chunk (C chunk L2-hot; pack = coalesced loads + ds_write_b128),
        // removing the Cb dependency so tmat overlaps cmean's HBM stream.
        uint4 (*CbL)[64] = (uint4(*)[64])smem_raw;    // [8][64] granules, 8 KB
        int r0 = b * 64;
        int w  = tid >> 6, l = tid & 63;
        int rowA = r0 + w*16 + (l & 15);
        int kq   = l >> 4;
        const float* xb = X + (size_t)rowA * DD + kq * 8;
        f32x4 acc[4];
        #pragma unroll
        for (int ng = 0; ng < 4; ++ng) acc[ng] = (f32x4){0.f, 0.f, 0.f, 0.f};
        for (int kc = 0; kc < DD; kc += 64) {
            __syncthreads();
            #pragma unroll
            for (int u = 0; u < 2; ++u) {
                // granule g=ks2*4+kg -> k-offset kc+8g (identity: ks2*32+kg*8 == 8g)
                int g = (tid >> 6) + u*4;             // 0..7
                int n = tid & 63;
                const float* cp = C + (size_t)(kc + g*8) * 64 + n;
                uint4 gr;
                gr.x = pk2(cp[0],   cp[64]);
                gr.y = pk2(cp[128], cp[192]);
                gr.z = pk2(cp[256], cp[320]);
                gr.w = pk2(cp[384], cp[448]);
                CbL[g][n] = gr;
            }
            __syncthreads();
            #pragma unroll
            for (int ks2 = 0; ks2 < 2; ++ks2) {
                float4 xa = *((const float4*)(xb + kc + ks2*32));
                float4 xc = *((const float4*)(xb + kc + ks2*32 + 4));
                B8 a;
                a.u[0] = pk2(xa.x, xa.y); a.u[1] = pk2(xa.z, xa.w);
                a.u[2] = pk2(xc.x, xc.y); a.u[3] = pk2(xc.z, xc.w);
                B8 b0, b1, b2, b3;
                b0.q = CbL[ks2*4 + kq][(l & 15)];
                b1.q = CbL[ks2*4 + kq][(l & 15) + 16];
                b2.q = CbL[ks2*4 + kq][(l & 15) + 32];
                b3.q = CbL[ks2*4 + kq][(l & 15) + 48];
                acc[0] = __builtin_amdgcn_mfma_f32_16x16x32_bf16(a.v, b0.v, acc[0], 0, 0, 0);
                acc[1] = __builtin_amdgcn_mfma_f32_16x16x32_bf16(a.v, b1.v, acc[1], 0, 0, 0);
                acc[2] = __builtin_amdgcn_mfma_f32_16x16x32_bf16(a.v, b2.v, acc[2], 0, 0, 0);
                acc[3] = __builtin_amdgcn_mfma_f32_16x16x32_bf16(a.v, b3.v, acc[3], 0, 0, 0);
            }
        }
        int rw = r0 + w*16 + kq * 4;
        #pragma unroll
        for (int ng = 0; ng < 4; ++ng) {
            int n = ng*16 + (l & 15);
            #pragma unroll
            for (int r = 0; r < 4; ++r)
                Tb[(size_t)(rw + r) * 64 + n] = f2bf(acc[ng][r]);
        }
    } else if (b < 1628) {
        // cmean partial over 25 samples; 5 loads in flight (verified R9 body)
        int q   = b - 128;
        int sp  = q & 3;
        int idx = (q >> 2) * 256 + tid;          // 375*256 == 500*192
        int r  = idx / 192;
        int d4 = idx % 192;
        const float4* base = (const float4*)clusters
                           + (size_t)r * CS * 192 + (size_t)sp * 25 * 192 + d4;
        float4 a0={0,0,0,0},a1={0,0,0,0},a2={0,0,0,0},a3={0,0,0,0},a4={0,0,0,0};
        for (int s = 0; s < 25; s += 5) {
            float4 v0 = base[(size_t)(s+0)*192];
            float4 v1 = base[(size_t)(s+1)*192];
            float4 v2 = base[(size_t)(s+2)*192];
            float4 v3 = base[(size_t)(s+3)*192];
            float4 v4 = base[(size_t)(s+4)*192];
            a0.x+=v0.x; a0.y+=v0.y; a0.z+=v0.z; a0.w+=v0.w;
            a1.x+=v1.x; a1.y+=v1.y; a1.z+=v1.z; a1.w+=v1.w;
            a2.x+=v2.x; a2.y+=v2.y; a2.z+=v2.z; a2.w+=v2.w;
            a3.x+=v3.x; a3.y+=v3.y; a3.z+=v3.z; a3.w+=v3.w;
            a4.x+=v4.x; a4.y+=v4.y; a4.z+=v4.z; a4.w+=v4.w;
        }
        float4 o;
        o.x = a0.x+a1.x+a2.x+a3.x+a4.x;
        o.y = a0.y+a1.y+a2.y+a3.y+a4.y;
        o.z = a0.z+a1.z+a2.z+a3.z+a4.z;
        o.w = a0.w+a1.w+a2.w+a3.w+a4.w;
        ((float4*)(cmP + (size_t)sp * 384000))[idx] = o;   // RAW; *0.01 at use
    } else if (b < 1884) {
        // gram k-split partials (verified R11 body)
        int q  = b - 1628;
        int j  = q & 63, ks = q >> 6;
        int i   = tid & 63;
        int seg = tid >> 6;
        int k0  = ks * 192 + seg * 48;
        float p = 0.f;
        for (int k = k0; k < k0 + 48; ++k)
            p += C[k * NC + i] * C[k * NC + j];
        float (*red)[64] = (float(*)[64])smem_raw;
        red[seg][i] = p;
        __syncthreads();
        if (seg == 0)
            gramP[(size_t)ks * 4096 + i * NC + j] =
                red[0][i] + red[1][i] + red[2][i] + red[3][i];
    } else {
        // U-partial = C^T[kslice] @ W[kslice][128 cols] (verified f32 body)
        int q  = b - 1884;
        int nt = q >> 2, ks = q & 3;
        int n0 = nt * 128, kb = ks * 192;
        float (*Cu)[68]  = (float(*)[68])smem_raw;               // [32][68]
        float (*Wu)[132] = (float(*)[132])(smem_raw + 8704);     // [32][132]
        int tx = tid & 15, ty = tid >> 4;
        float4 a0[4], a1[4];
        #pragma unroll
        for (int i = 0; i < 4; ++i) { a0[i] = make_float4(0,0,0,0); a1[i] = make_float4(0,0,0,0); }
        for (int kc = kb; kc < kb + 192; kc += 32) {
            __syncthreads();
            {   int i4 = tid & 15, kk = tid >> 4;
                *((float4*)&Cu[kk][i4*4])    = *((const float4*)(C + (size_t)(kc+kk)*64 + i4*4));
                *((float4*)&Cu[kk+16][i4*4]) = *((const float4*)(C + (size_t)(kc+kk+16)*64 + i4*4));
            }
            {   int nf = tid & 31, kq2 = tid >> 5;
                #pragma unroll
                for (int u = 0; u < 4; ++u) {
                    int k = kq2 + u * 8;
                    int n = n0 + nf * 4;
                    float4 v = {0.f, 0.f, 0.f, 0.f};
                    if (n < NY) v = *((const float4*)(W + (size_t)(kc + k) * NY + n));
                    *((float4*)&Wu[k][nf*4]) = v;
                }
            }
            __syncthreads();
            #pragma unroll 8
            for (int k = 0; k < 32; ++k) {
                float4 ci = *((float4*)&Cu[k][ty*4]);
                float4 w0 = *((float4*)&Wu[k][tx*8]);
                float4 w1 = *((float4*)&Wu[k][tx*8+4]);
                FMA4(a0[0], ci.x, w0); FMA4(a1[0], ci.x, w1);
                FMA4(a0[1], ci.y, w0); FMA4(a1[1], ci.y, w1);
                FMA4(a0[2], ci.z, w0); FMA4(a1[2], ci.z, w1);
                FMA4(a0[3], ci.w, w0); FMA4(a1[3], ci.w, w1);
            }
        }
        float* Ups = Up + (size_t)ks * 64000;
        #pragma unroll
        for (int i = 0; i < 4; ++i) {
            int irow = ty * 4 + i;
            int n = n0 + tx * 8;
            if (n < NY)     *((float4*)(Ups + (size_t)irow * NY + n))     = a0[i];
            if (n + 4 < NY) *((float4*)(Ups + (size_t)irow * NY + n + 4)) = a1[i];
        }
    }
}

// ===== K2: inv (block 0) || score partials (blocks 1..16) =====
__global__ __launch_bounds__(256) void k_mid(
    const float* __restrict__ gramP, const float* __restrict__ cmP,
    const float* __restrict__ C, float* __restrict__ ginv,
    float* __restrict__ SP) {
    __shared__ __align__(16) char smem_raw[52224];
    int blk = blockIdx.x, tid = threadIdx.x;
    if (blk == 0) {
        // register-resident Gauss-Jordan; gram = sum of 4 k-split partials
        int c = tid & 63;
        int q = tid >> 6;
        float a[16], bb[16];
        #pragma unroll
        for (int i = 0; i < 16; ++i) {
            int r = q * 16 + i;
            size_t off = (size_t)r * 64 + c;
            a[i]  = gramP[off] + gramP[4096 + off] + gramP[8192 + off] + gramP[12288 + off];
            bb[i] = (r == c) ? 1.f : 0.f;
        }
        __shared__ float asr[2][64];
        __shared__ float bsr[2][64];
        for (int p = 0; p < 64; ++p) {
            int qp  = p >> 4;
            int lp  = p & 15;
            int par = p & 1;
            if (q == qp) {
                float ap = 0.f, bp = 0.f;
                #pragma unroll
                for (int i = 0; i < 16; ++i)
                    if (i == lp) { ap = a[i]; bp = bb[i]; }
                float App = __shfl(ap, p);
                float s   = 1.0f / App;
                asr[par][c] = ap * s;
                bsr[par][c] = bp * s;
            }
            __syncthreads();
            float as_ = asr[par][c];
            float bs_ = bsr[par][c];
            #pragma unroll
            for (int i = 0; i < 16; ++i) {
                float f = __shfl(a[i], p);
                bool isp = (q == qp) && (i == lp);
                a[i]  = isp ? as_ : fmaf(-f, as_, a[i]);
                bb[i] = isp ? bs_ : fmaf(-f, bs_, bb[i]);
            }
        }
        #pragma unroll
        for (int i = 0; i < 16; ++i)
            ginv[(q * 16 + i) * 64 + c] = bb[i];
    } else {
        // SP-partial = cm[128 rows][192-k slice] @ C; cm = 0.01*sum(4 partials)
        int q = blk - 1;
        int tile = q >> 2, ks = q & 3;
        int r0 = tile * 128, kb = ks * 192;
        float (*Mr)[68] = (float(*)[68])smem_raw;                 // [128][68]
        float (*Cs)[68] = (float(*)[68])(smem_raw + 128*68*4);    // [64][68]
        int tx = tid & 15, ty = tid >> 4;
        float4 acc[8];
        #pragma unroll
        for (int r = 0; r < 8; ++r) acc[r] = make_float4(0.f,0.f,0.f,0.f);
        for (int kc = 0; kc < 192; kc += 64) {
            __syncthreads();
            #pragma unroll
            for (int p = 0; p < 8; ++p) {
                int f = tid + p * 256;
                int row = f >> 4, k4 = f & 15;
                int gr = r0 + row;
                int grc = gr < NCL ? gr : (NCL - 1);
                size_t off = (size_t)grc*DD + kb + kc + k4*4;
                float4 c0 = *((const float4*)(cmP + off));
                float4 c1 = *((const float4*)(cmP + 384000 + off));
                float4 c2 = *((const float4*)(cmP + 768000 + off));
                float4 c3 = *((const float4*)(cmP + 1152000 + off));
                float4 m;
                m.x = (c0.x+c1.x+c2.x+c3.x) * 0.01f;
                m.y = (c0.y+c1.y+c2.y+c3.y) * 0.01f;
                m.z = (c0.z+c1.z+c2.z+c3.z) * 0.01f;
                m.w = (c0.w+c1.w+c2.w+c3.w) * 0.01f;
                *((float4*)&Mr[row][k4*4]) = m;
            }
            #pragma unroll
            for (int p = 0; p < 4; ++p) {
                int f = tid + p * 256;
                int k = f >> 4, c4 = f & 15;
                *((float4*)&Cs[k][c4*4]) =
                    *((const float4*)(C + (size_t)(kb+kc+k)*64 + c4*4));
            }
            __syncthreads();
            for (int k0 = 0; k0 < 64; k0 += 4) {
                float4 cv0 = *((float4*)&Cs[k0+0][tx*4]);
                float4 cv1 = *((float4*)&Cs[k0+1][tx*4]);
                float4 cv2 = *((float4*)&Cs[k0+2][tx*4]);
                float4 cv3 = *((float4*)&Cs[k0+3][tx*4]);
                #pragma unroll
                for (int r = 0; r < 8; ++r) {
                    float4 xv = *((float4*)&Mr[ty*8+r][k0]);
                    FMA4(acc[r], xv.x, cv0);
                    FMA4(acc[r], xv.y, cv1);
                    FMA4(acc[r], xv.z, cv2);
                    FMA4(acc[r], xv.w, cv3);
                }
            }
        }
        float* SPs = SP + (size_t)ks * 32000;
        #pragma unroll
        for (int r = 0; r < 8; ++r) {
            int row = r0 + ty * 8 + r;
            if (row < NCL)
                *((float4*)(SPs + (size_t)row * 64 + tx*4)) = acc[r];
        }
    }
}

// ====== K3: Vb = bf16[(Ginv @ sum Up)^T] granules (0..15) || sparse (16) ======
__global__ __launch_bounds__(256) void k_vc(
    const float* __restrict__ ginv, const float* __restrict__ Up,
    float* __restrict__ SP, unsigned short* __restrict__ Vb,
    float* __restrict__ out2) {
    __shared__ __align__(16) char smem_raw[34816];
    int blk = blockIdx.x, tid = threadIdx.x;
    if (blk == 16) {
        // sparse losses (verified body)
        __shared__ float colred[4][64];
        __shared__ float rn[64];
        __shared__ float trc[64];
        __shared__ float r1[4], r2[4];
        const float* SP0 = SP;
        const float* SP1 = SP + 32000;
        const float* SP2 = SP + 64000;
        const float* SP3 = SP + 96000;
        int c = tid & 63, seg = tid >> 6;
        float p = 0.f;
        for (int r = seg; r < NCL; r += 4) {
            int off = r * 64 + c;
            float s = fabsf(SP0[off] + SP1[off] + SP2[off] + SP3[off]);
            SP[off] = s;
            p += s * s;
        }
        colred[seg][c] = p;
        __syncthreads();
        if (seg == 0) {
            float n2  = colred[0][c] + colred[1][c] + colred[2][c] + colred[3][c];
            float inv = 1.0f / fmaxf(sqrtf(n2), EPSN);
            rn[c]  = inv;
            trc[c] = n2 * inv * inv;
        }
        __syncthreads();
        float l1p = 0.f, l2p = 0.f;
        for (int r = tid; r < NCL; r += 256) {
            float rs = 0.f;
            #pragma unroll
            for (int cc = 0; cc < 64; ++cc)
                rs += SP[r * 64 + cc] * rn[cc];
            l1p += rs;
            l2p += rs * rs;
        }
        #pragma unroll
        for (int off = 32; off > 0; off >>= 1) {
            l1p += __shfl_down(l1p, off);
            l2p += __shfl_down(l2p, off);
        }
        int wave = tid >> 6, lane = tid & 63;
        if (lane == 0) { r1[wave] = l1p; r2[wave] = l2p; }
        __syncthreads();
        if (tid == 0) {
            float L1 = r1[0] + r1[1] + r1[2] + r1[3];
            float L2 = r2[0] + r2[1] + r2[2] + r2[3];
            float tr = 0.f;
            #pragma unroll
            for (int cc = 0; cc < 64; ++cc) tr += trc[cc];
            out2[0] = L1;
            out2[1] = L2 - tr;
        }
        return;
    }
    // V = Ginv @ Usum (f32), emitted transposed bf16 (B-fragment layout)
    float (*Us)[68] = (float(*)[68])smem_raw;                     // [64][68]
    float (*Gs)[68] = (float(*)[68])(smem_raw + 64*68*4);         // [64][68]
    int c0 = blk * 64;
    int tx = tid & 15, ty = tid >> 4;
    const float* Up0 = Up;
    const float* Up1 = Up + 64000;
    const float* Up2 = Up + 128000;
    const float* Up3 = Up + 192000;
    #pragma unroll
    for (int p = 0; p < 4; ++p) {
        int f = tid + p * 256;
        int j = f >> 4, n4 = f & 15;
        int n = c0 + n4 * 4;
        float4 v = {0.f, 0.f, 0.f, 0.f};
        if (n < NY) {
            float4 u0 = *((const float4*)(Up0 + (size_t)j * NY + n));
            float4 u1 = *((const float4*)(Up1 + (size_t)j * NY + n));
            float4 u2 = *((const float4*)(Up2 + (size_t)j * NY + n));
            float4 u3 = *((const float4*)(Up3 + (size_t)j * NY + n));
            v.x = u0.x + u1.x + u2.x + u3.x;
            v.y = u0.y + u1.y + u2.y + u3.y;
            v.z = u0.z + u1.z + u2.z + u3.z;
            v.w = u0.w + u1.w + u2.w + u3.w;
        }
        *((float4*)&Us[j][n4*4]) = v;
        *((float4*)&Gs[j][n4*4]) = *((const float4*)(ginv + (size_t)j * 64 + n4*4));
    }
    __syncthreads();
    float4 acc[4];
    #pragma unroll
    for (int i = 0; i < 4; ++i) acc[i] = make_float4(0.f,0.f,0.f,0.f);
    for (int j0 = 0; j0 < 64; j0 += 4) {
        #pragma unroll
        for (int jj = 0; jj < 4; ++jj) {
            float4 g = *((float4*)&Gs[j0+jj][ty*4]);   // Ginv symmetric
            float4 u = *((float4*)&Us[j0+jj][tx*4]);
            FMA4(acc[0], g.x, u);
            FMA4(acc[1], g.y, u);
            FMA4(acc[2], g.z, u);
            FMA4(acc[3], g.w, u);
        }
    }
    #pragma unroll
    for (int i = 0; i < 4; ++i) {
        int krow = ty * 4 + i;
        Vb[(size_t)(c0 + tx*4 + 0) * 64 + krow] = f2bf(acc[i].x);
        Vb[(size_t)(c0 + tx*4 + 1) * 64 + krow] = f2bf(acc[i].y);
        Vb[(size_t)(c0 + tx*4 + 2) * 64 + krow] = f2bf(acc[i].z);
        Vb[(size_t)(c0 + tx*4 + 3) * 64 + krow] = f2bf(acc[i].w);
    }
}

// ============ K4: y = T @ V + b via MFMA, 128x128 tile, zero LDS ============
__global__ __launch_bounds__(256) void k_ypred(
    const uint4* __restrict__ Tb, const uint4* __restrict__ Vbq,
    const float* __restrict__ bh, float* __restrict__ Y) {
    int blk = blockIdx.x, tid = threadIdx.x;
    int rb = blk >> 3, cb = blk & 7;
    int r0g = rb * 128, c0g = cb * 128;
    int w = tid >> 6, l = tid & 63;
    int wr = (w >> 1) * 64, wc = (w & 1) * 64;
    int kq = l >> 4, ln = l & 15;
    f32x4 acc[4][4];
    #pragma unroll
    for (int rg = 0; rg < 4; ++rg)
        #pragma unroll
        for (int ng = 0; ng < 4; ++ng) acc[rg][ng] = (f32x4){0.f,0.f,0.f,0.f};
    #pragma unroll
    for (int ks = 0; ks < 2; ++ks) {
        B8 a[4], bb[4];
        #pragma unroll
        for (int rg = 0; rg < 4; ++rg) {
            int row = r0g + wr + rg*16 + ln;
            a[rg].q = Tb[(size_t)row * 8 + ks*4 + kq];
        }
        #pragma unroll
        for (int ng = 0; ng < 4; ++ng) {
            int n = c0g + wc + ng*16 + ln;
            bb[ng].q = Vbq[(size_t)n * 8 + ks*4 + kq];
        }
        #pragma unroll
        for (int rg = 0; rg < 4; ++rg)
            #pragma unroll
            for (int ng = 0; ng < 4; ++ng)
                acc[rg][ng] = __builtin_amdgcn_mfma_f32_16x16x32_bf16(
                    a[rg].v, bb[ng].v, acc[rg][ng], 0, 0, 0);
    }
    #pragma unroll
    for (int ng = 0; ng < 4; ++ng) {
        int n = c0g + wc + ng*16 + ln;
        if (n < NY) {
            float bias = bh[n];
            #pragma unroll
            for (int rg = 0; rg < 4; ++rg) {
                int row = r0g + wr + rg*16 + kq*4;
                #pragma unroll
                for (int r = 0; r < 4; ++r)
                    Y[(size_t)(row + r) * NY + n] = acc[rg][ng][r] + bias;
            }
        }
    }
}

extern "C" void kernel_launch(void* const* d_in, const int* in_sizes, int n_in,
                              void* d_out, int out_size, void* d_ws, size_t ws_size,
                              hipStream_t stream) {
    const float* X        = (const float*)d_in[0];   // [8192,768]
    const float* clusters = (const float*)d_in[1];   // [500,100,768]
    const float* C        = (const float*)d_in[2];   // [768,64]
    const float* W        = (const float*)d_in[3];   // [768,1000]
    const float* bh       = (const float*)d_in[4];   // [1000]
    float* out = (float*)d_out;                      // y_pred, L1, L2
    float* ws  = (float*)d_ws;

    float* cmP   = ws;                    // 4 x 384000 = 1,536,000
    float* gramP = cmP   + 1536000;       // 4 x 4096 = 16384
    float* ginv  = gramP + 16384;         // 4096
    float* Up    = ginv  + 4096;          // 4 x 64000 = 256000
    float* SP    = Up    + 256000;        // 4 x 32000 = 128000
    float* TbF   = SP    + 128000;        // 262144 floats (Tb bf16)
    float* VbF   = TbF   + 262144;        // 32768 floats (Vb bf16)

    unsigned short* Tb  = (unsigned short*)TbF;
    unsigned short* Vb  = (unsigned short*)VbF;

    k_front <<<dim3(1916), dim3(256), 0, stream>>>(clusters, C, W, X, cmP, gramP, Up, Tb);
    k_mid   <<<dim3(17),   dim3(256), 0, stream>>>(gramP, cmP, C, ginv, SP);
    k_vc    <<<dim3(17),   dim3(256), 0, stream>>>(ginv, Up, SP, Vb, out + (size_t)BS * NY);
    k_ypred <<<dim3(512),  dim3(256), 0, stream>>>((const uint4*)Tb, (const uint4*)Vb, bh, out);
}

// Round 14
// 146.597 us; speedup vs baseline: 1.0984x; 1.0984x over previous
//
#include <hip/hip_runtime.h>
#include <hip/hip_bf16.h>
#include <math.h>

#define BS   8192
#define DD   768
#define NC   64
#define NCL  500
#define CS   100
#define NY   1000
#define EPSN 1e-12f

typedef __attribute__((ext_vector_type(8))) short bf16x8;
typedef __attribute__((ext_vector_type(4))) float f32x4;

union B8 { unsigned u[4]; bf16x8 v; uint4 q; };

__device__ inline unsigned short f2bf(float x) {
    __hip_bfloat16 h = __float2bfloat16(x);
    return *reinterpret_cast<unsigned short*>(&h);
}
__device__ inline unsigned pk2(float a, float b) {
    return (unsigned)f2bf(a) | ((unsigned)f2bf(b) << 16);
}

#define FMA4(acc, s, v) { (acc).x = fmaf((s), (v).x, (acc).x); \
                          (acc).y = fmaf((s), (v).y, (acc).y); \
                          (acc).z = fmaf((s), (v).z, (acc).z); \
                          (acc).w = fmaf((s), (v).w, (acc).w); }

// ===== K1: scoreGEMM MFMA (200) || tmat MFMA (128) || gram ksplit (256) || U (32) =====
// R13 change: cmean DELETED. score_raw = clusters_flat[500 x 76800] @ C-rep,
// computed by MFMA with deep load pipelining (cmean's latency chain was the
// invisible 88us floor: replays showed 88us at 8.7MB HBM, all pipes idle).
// Scale factors (1/100, colnorms) cancel in the normalized losses.
__global__ __launch_bounds__(256) void k_front(
    const float* __restrict__ clusters, const float* __restrict__ C,
    const float* __restrict__ W, const float* __restrict__ X,
    float* __restrict__ gramP, float* __restrict__ Up,
    float* __restrict__ SP, unsigned short* __restrict__ Tb) {
    __shared__ __align__(16) char smem_raw[25600];
    int b = blockIdx.x, tid = threadIdx.x;
    if (b < 200) {
        // score partial: rows rt*64..+63, samples sp*4..+3 (K-eff = 4*768)
        int rt = b / 25, sp = b % 25;
        uint4 (*CbL)[64] = (uint4(*)[64])smem_raw;    // [8][64] C granules, 8 KB
        int r0 = rt * 64;
        int w  = tid >> 6, l = tid & 63;
        int rowA = r0 + w*16 + (l & 15);
        int rcl  = rowA < NCL ? rowA : (NCL - 1);     // clamp; rows >=500 unread
        int kq   = l >> 4;
        const float* ab = clusters + (size_t)rcl * CS * DD + (size_t)sp * 4 * DD + kq * 8;
        f32x4 acc[4];
        #pragma unroll
        for (int ng = 0; ng < 4; ++ng) acc[ng] = (f32x4){0.f, 0.f, 0.f, 0.f};
        for (int kc = 0; kc < DD; kc += 64) {
            __syncthreads();
            #pragma unroll
            for (int u = 0; u < 2; ++u) {             // pack C[kc..kc+64) granules
                int g = (tid >> 6) + u*4;
                int n = tid & 63;
                const float* cp = C + (size_t)(kc + g*8) * 64 + n;
                uint4 gr;
                gr.x = pk2(cp[0],   cp[64]);
                gr.y = pk2(cp[128], cp[192]);
                gr.z = pk2(cp[256], cp[320]);
                gr.w = pk2(cp[384], cp[448]);
                CbL[g][n] = gr;
            }
            __syncthreads();
            #pragma unroll
            for (int ss = 0; ss < 4; ++ss) {          // 4 samples reuse the pack
                #pragma unroll
                for (int ks2 = 0; ks2 < 2; ++ks2) {
                    const float* ap = ab + (size_t)ss * DD + kc + ks2*32;
                    float4 xa = *((const float4*)ap);
                    float4 xc = *((const float4*)(ap + 4));
                    B8 a;
                    a.u[0] = pk2(xa.x, xa.y); a.u[1] = pk2(xa.z, xa.w);
                    a.u[2] = pk2(xc.x, xc.y); a.u[3] = pk2(xc.z, xc.w);
                    B8 b0, b1, b2, b3;
                    b0.q = CbL[ks2*4 + kq][(l & 15)];
                    b1.q = CbL[ks2*4 + kq][(l & 15) + 16];
                    b2.q = CbL[ks2*4 + kq][(l & 15) + 32];
                    b3.q = CbL[ks2*4 + kq][(l & 15) + 48];
                    acc[0] = __builtin_amdgcn_mfma_f32_16x16x32_bf16(a.v, b0.v, acc[0], 0, 0, 0);
                    acc[1] = __builtin_amdgcn_mfma_f32_16x16x32_bf16(a.v, b1.v, acc[1], 0, 0, 0);
                    acc[2] = __builtin_amdgcn_mfma_f32_16x16x32_bf16(a.v, b2.v, acc[2], 0, 0, 0);
                    acc[3] = __builtin_amdgcn_mfma_f32_16x16x32_bf16(a.v, b3.v, acc[3], 0, 0, 0);
                }
            }
        }
        int rw = r0 + w*16 + kq * 4;                  // D layout (m89)
        float* SPs = SP + (size_t)sp * 32768;         // 512x64 per partial
        #pragma unroll
        for (int ng = 0; ng < 4; ++ng) {
            int n = ng*16 + (l & 15);
            #pragma unroll
            for (int r = 0; r < 4; ++r)
                SPs[(size_t)(rw + r) * 64 + n] = acc[ng][r];
        }
    } else if (b < 328) {
        // T = X @ C via MFMA, self-packed C granules (verified R12 body)
        uint4 (*CbL)[64] = (uint4(*)[64])smem_raw;
        int r0 = (b - 200) * 64;
        int w  = tid >> 6, l = tid & 63;
        int rowA = r0 + w*16 + (l & 15);
        int kq   = l >> 4;
        const float* xb = X + (size_t)rowA * DD + kq * 8;
        f32x4 acc[4];
        #pragma unroll
        for (int ng = 0; ng < 4; ++ng) acc[ng] = (f32x4){0.f, 0.f, 0.f, 0.f};
        for (int kc = 0; kc < DD; kc += 64) {
            __syncthreads();
            #pragma unroll
            for (int u = 0; u < 2; ++u) {
                int g = (tid >> 6) + u*4;
                int n = tid & 63;
                const float* cp = C + (size_t)(kc + g*8) * 64 + n;
                uint4 gr;
                gr.x = pk2(cp[0],   cp[64]);
                gr.y = pk2(cp[128], cp[192]);
                gr.z = pk2(cp[256], cp[320]);
                gr.w = pk2(cp[384], cp[448]);
                CbL[g][n] = gr;
            }
            __syncthreads();
            #pragma unroll
            for (int ks2 = 0; ks2 < 2; ++ks2) {
                float4 xa = *((const float4*)(xb + kc + ks2*32));
                float4 xc = *((const float4*)(xb + kc + ks2*32 + 4));
                B8 a;
                a.u[0] = pk2(xa.x, xa.y); a.u[1] = pk2(xa.z, xa.w);
                a.u[2] = pk2(xc.x, xc.y); a.u[3] = pk2(xc.z, xc.w);
                B8 b0, b1, b2, b3;
                b0.q = CbL[ks2*4 + kq][(l & 15)];
                b1.q = CbL[ks2*4 + kq][(l & 15) + 16];
                b2.q = CbL[ks2*4 + kq][(l & 15) + 32];
                b3.q = CbL[ks2*4 + kq][(l & 15) + 48];
                acc[0] = __builtin_amdgcn_mfma_f32_16x16x32_bf16(a.v, b0.v, acc[0], 0, 0, 0);
                acc[1] = __builtin_amdgcn_mfma_f32_16x16x32_bf16(a.v, b1.v, acc[1], 0, 0, 0);
                acc[2] = __builtin_amdgcn_mfma_f32_16x16x32_bf16(a.v, b2.v, acc[2], 0, 0, 0);
                acc[3] = __builtin_amdgcn_mfma_f32_16x16x32_bf16(a.v, b3.v, acc[3], 0, 0, 0);
            }
        }
        int rw = r0 + w*16 + kq * 4;
        #pragma unroll
        for (int ng = 0; ng < 4; ++ng) {
            int n = ng*16 + (l & 15);
            #pragma unroll
            for (int r = 0; r < 4; ++r)
                Tb[(size_t)(rw + r) * 64 + n] = f2bf(acc[ng][r]);
        }
    } else if (b < 584) {
        // gram k-split partials (verified R11 body)
        int q  = b - 328;
        int j  = q & 63, ks = q >> 6;
        int i   = tid & 63;
        int seg = tid >> 6;
        int k0  = ks * 192 + seg * 48;
        float p = 0.f;
        for (int k = k0; k < k0 + 48; ++k)
            p += C[k * NC + i] * C[k * NC + j];
        float (*red)[64] = (float(*)[64])smem_raw;
        red[seg][i] = p;
        __syncthreads();
        if (seg == 0)
            gramP[(size_t)ks * 4096 + i * NC + j] =
                red[0][i] + red[1][i] + red[2][i] + red[3][i];
    } else {
        // U-partial = C^T[kslice] @ W[kslice][128 cols] (verified f32 body)
        int q  = b - 584;
        int nt = q >> 2, ks = q & 3;
        int n0 = nt * 128, kb = ks * 192;
        float (*Cu)[68]  = (float(*)[68])smem_raw;               // [32][68]
        float (*Wu)[132] = (float(*)[132])(smem_raw + 8704);     // [32][132]
        int tx = tid & 15, ty = tid >> 4;
        float4 a0[4], a1[4];
        #pragma unroll
        for (int i = 0; i < 4; ++i) { a0[i] = make_float4(0,0,0,0); a1[i] = make_float4(0,0,0,0); }
        for (int kc = kb; kc < kb + 192; kc += 32) {
            __syncthreads();
            {   int i4 = tid & 15, kk = tid >> 4;
                *((float4*)&Cu[kk][i4*4])    = *((const float4*)(C + (size_t)(kc+kk)*64 + i4*4));
                *((float4*)&Cu[kk+16][i4*4]) = *((const float4*)(C + (size_t)(kc+kk+16)*64 + i4*4));
            }
            {   int nf = tid & 31, kq2 = tid >> 5;
                #pragma unroll
                for (int u = 0; u < 4; ++u) {
                    int k = kq2 + u * 8;
                    int n = n0 + nf * 4;
                    float4 v = {0.f, 0.f, 0.f, 0.f};
                    if (n < NY) v = *((const float4*)(W + (size_t)(kc + k) * NY + n));
                    *((float4*)&Wu[k][nf*4]) = v;
                }
            }
            __syncthreads();
            #pragma unroll 8
            for (int k = 0; k < 32; ++k) {
                float4 ci = *((float4*)&Cu[k][ty*4]);
                float4 w0 = *((float4*)&Wu[k][tx*8]);
                float4 w1 = *((float4*)&Wu[k][tx*8+4]);
                FMA4(a0[0], ci.x, w0); FMA4(a1[0], ci.x, w1);
                FMA4(a0[1], ci.y, w0); FMA4(a1[1], ci.y, w1);
                FMA4(a0[2], ci.z, w0); FMA4(a1[2], ci.z, w1);
                FMA4(a0[3], ci.w, w0); FMA4(a1[3], ci.w, w1);
            }
        }
        float* Ups = Up + (size_t)ks * 64000;
        #pragma unroll
        for (int i = 0; i < 4; ++i) {
            int irow = ty * 4 + i;
            int n = n0 + tx * 8;
            if (n < NY)     *((float4*)(Ups + (size_t)irow * NY + n))     = a0[i];
            if (n + 4 < NY) *((float4*)(Ups + (size_t)irow * NY + n + 4)) = a1[i];
        }
    }
}

// ===== K2: inv (block 0) || S-reduce 25->1 + abs (blocks 1..8) =====
__global__ __launch_bounds__(256) void k_mid(
    const float* __restrict__ gramP, const float* __restrict__ SP,
    float* __restrict__ ginv, float* __restrict__ Sfin) {
    int blk = blockIdx.x, tid = threadIdx.x;
    if (blk == 0) {
        // register-resident Gauss-Jordan; gram = sum of 4 k-split partials
        int c = tid & 63;
        int q = tid >> 6;
        float a[16], bb[16];
        #pragma unroll
        for (int i = 0; i < 16; ++i) {
            int r = q * 16 + i;
            size_t off = (size_t)r * 64 + c;
            a[i]  = gramP[off] + gramP[4096 + off] + gramP[8192 + off] + gramP[12288 + off];
            bb[i] = (r == c) ? 1.f : 0.f;
        }
        __shared__ float asr[2][64];
        __shared__ float bsr[2][64];
        for (int p = 0; p < 64; ++p) {
            int qp  = p >> 4;
            int lp  = p & 15;
            int par = p & 1;
            if (q == qp) {
                float ap = 0.f, bp = 0.f;
                #pragma unroll
                for (int i = 0; i < 16; ++i)
                    if (i == lp) { ap = a[i]; bp = bb[i]; }
                float App = __shfl(ap, p);
                float s   = 1.0f / App;
                asr[par][c] = ap * s;
                bsr[par][c] = bp * s;
            }
            __syncthreads();
            float as_ = asr[par][c];
            float bs_ = bsr[par][c];
            #pragma unroll
            for (int i = 0; i < 16; ++i) {
                float f = __shfl(a[i], p);
                bool isp = (q == qp) && (i == lp);
                a[i]  = isp ? as_ : fmaf(-f, as_, a[i]);
                bb[i] = isp ? bs_ : fmaf(-f, bs_, bb[i]);
            }
        }
        #pragma unroll
        for (int i = 0; i < 16; ++i)
            ginv[(q * 16 + i) * 64 + c] = bb[i];
    } else {
        // S-reduce: Sfin = |sum of 25 score partials| over rows 0..499
        int e = blk - 1;                              // 0..7, 4000 floats each
        for (int t = tid; t < 1000; t += 256) {
            size_t off = (size_t)e * 4000 + (size_t)t * 4;
            float4 s = {0.f, 0.f, 0.f, 0.f};
            #pragma unroll
            for (int p = 0; p < 25; ++p) {
                float4 v = *((const float4*)(SP + (size_t)p * 32768 + off));
                s.x += v.x; s.y += v.y; s.z += v.z; s.w += v.w;
            }
            float4 o = {fabsf(s.x), fabsf(s.y), fabsf(s.z), fabsf(s.w)};
            *((float4*)(Sfin + off)) = o;
        }
    }
}

// ====== K3: Vb = bf16[(Ginv @ sum Up)^T] granules (0..15) || sparse (16) ======
__global__ __launch_bounds__(256) void k_vc(
    const float* __restrict__ ginv, const float* __restrict__ Up,
    const float* __restrict__ Sfin, unsigned short* __restrict__ Vb,
    float* __restrict__ out2) {
    __shared__ __align__(16) char smem_raw[34816];
    int blk = blockIdx.x, tid = threadIdx.x;
    if (blk == 16) {
        // sparse losses from Sfin (colnorm cancellation; verified logic)
        __shared__ float colred[4][64];
        __shared__ float rn[64];
        __shared__ float trc[64];
        __shared__ float r1[4], r2[4];
        int c = tid & 63, seg = tid >> 6;
        float p = 0.f;
        for (int r = seg; r < NCL; r += 4) {
            float s = Sfin[r * 64 + c];
            p += s * s;
        }
        colred[seg][c] = p;
        __syncthreads();
        if (seg == 0) {
            float n2  = colred[0][c] + colred[1][c] + colred[2][c] + colred[3][c];
            float inv = 1.0f / fmaxf(sqrtf(n2), EPSN);
            rn[c]  = inv;
            trc[c] = n2 * inv * inv;
        }
        __syncthreads();
        float l1p = 0.f, l2p = 0.f;
        for (int r = tid; r < NCL; r += 256) {
            float rs = 0.f;
            #pragma unroll
            for (int cc = 0; cc < 64; ++cc)
                rs += Sfin[r * 64 + cc] * rn[cc];
            l1p += rs;
            l2p += rs * rs;
        }
        #pragma unroll
        for (int off = 32; off > 0; off >>= 1) {
            l1p += __shfl_down(l1p, off);
            l2p += __shfl_down(l2p, off);
        }
        int wave = tid >> 6, lane = tid & 63;
        if (lane == 0) { r1[wave] = l1p; r2[wave] = l2p; }
        __syncthreads();
        if (tid == 0) {
            float L1 = r1[0] + r1[1] + r1[2] + r1[3];
            float L2 = r2[0] + r2[1] + r2[2] + r2[3];
            float tr = 0.f;
            #pragma unroll
            for (int cc = 0; cc < 64; ++cc) tr += trc[cc];
            out2[0] = L1;
            out2[1] = L2 - tr;
        }
        return;
    }
    // V = Ginv @ Usum (f32), emitted transposed bf16 (verified body)
    float (*Us)[68] = (float(*)[68])smem_raw;                     // [64][68]
    float (*Gs)[68] = (float(*)[68])(smem_raw + 64*68*4);         // [64][68]
    int c0 = blk * 64;
    int tx = tid & 15, ty = tid >> 4;
    const float* Up0 = Up;
    const float* Up1 = Up + 64000;
    const float* Up2 = Up + 128000;
    const float* Up3 = Up + 192000;
    #pragma unroll
    for (int p = 0; p < 4; ++p) {
        int f = tid + p * 256;
        int j = f >> 4, n4 = f & 15;
        int n = c0 + n4 * 4;
        float4 v = {0.f, 0.f, 0.f, 0.f};
        if (n < NY) {
            float4 u0 = *((const float4*)(Up0 + (size_t)j * NY + n));
            float4 u1 = *((const float4*)(Up1 + (size_t)j * NY + n));
            float4 u2 = *((const float4*)(Up2 + (size_t)j * NY + n));
            float4 u3 = *((const float4*)(Up3 + (size_t)j * NY + n));
            v.x = u0.x + u1.x + u2.x + u3.x;
            v.y = u0.y + u1.y + u2.y + u3.y;
            v.z = u0.z + u1.z + u2.z + u3.z;
            v.w = u0.w + u1.w + u2.w + u3.w;
        }
        *((float4*)&Us[j][n4*4]) = v;
        *((float4*)&Gs[j][n4*4]) = *((const float4*)(ginv + (size_t)j * 64 + n4*4));
    }
    __syncthreads();
    float4 acc[4];
    #pragma unroll
    for (int i = 0; i < 4; ++i) acc[i] = make_float4(0.f,0.f,0.f,0.f);
    for (int j0 = 0; j0 < 64; j0 += 4) {
        #pragma unroll
        for (int jj = 0; jj < 4; ++jj) {
            float4 g = *((float4*)&Gs[j0+jj][ty*4]);   // Ginv symmetric
            float4 u = *((float4*)&Us[j0+jj][tx*4]);
            FMA4(acc[0], g.x, u);
            FMA4(acc[1], g.y, u);
            FMA4(acc[2], g.z, u);
            FMA4(acc[3], g.w, u);
        }
    }
    #pragma unroll
    for (int i = 0; i < 4; ++i) {
        int krow = ty * 4 + i;
        Vb[(size_t)(c0 + tx*4 + 0) * 64 + krow] = f2bf(acc[i].x);
        Vb[(size_t)(c0 + tx*4 + 1) * 64 + krow] = f2bf(acc[i].y);
        Vb[(size_t)(c0 + tx*4 + 2) * 64 + krow] = f2bf(acc[i].z);
        Vb[(size_t)(c0 + tx*4 + 3) * 64 + krow] = f2bf(acc[i].w);
    }
}

// ============ K4: y = T @ V + b via MFMA, 128x128 tile, zero LDS ============
__global__ __launch_bounds__(256) void k_ypred(
    const uint4* __restrict__ Tb, const uint4* __restrict__ Vbq,
    const float* __restrict__ bh, float* __restrict__ Y) {
    int blk = blockIdx.x, tid = threadIdx.x;
    int rb = blk >> 3, cb = blk & 7;
    int r0g = rb * 128, c0g = cb * 128;
    int w = tid >> 6, l = tid & 63;
    int wr = (w >> 1) * 64, wc = (w & 1) * 64;
    int kq = l >> 4, ln = l & 15;
    f32x4 acc[4][4];
    #pragma unroll
    for (int rg = 0; rg < 4; ++rg)
        #pragma unroll
        for (int ng = 0; ng < 4; ++ng) acc[rg][ng] = (f32x4){0.f,0.f,0.f,0.f};
    #pragma unroll
    for (int ks = 0; ks < 2; ++ks) {
        B8 a[4], bb[4];
        #pragma unroll
        for (int rg = 0; rg < 4; ++rg) {
            int row = r0g + wr + rg*16 + ln;
            a[rg].q = Tb[(size_t)row * 8 + ks*4 + kq];
        }
        #pragma unroll
        for (int ng = 0; ng < 4; ++ng) {
            int n = c0g + wc + ng*16 + ln;
            bb[ng].q = Vbq[(size_t)n * 8 + ks*4 + kq];
        }
        #pragma unroll
        for (int rg = 0; rg < 4; ++rg)
            #pragma unroll
            for (int ng = 0; ng < 4; ++ng)
                acc[rg][ng] = __builtin_amdgcn_mfma_f32_16x16x32_bf16(
                    a[rg].v, bb[ng].v, acc[rg][ng], 0, 0, 0);
    }
    #pragma unroll
    for (int ng = 0; ng < 4; ++ng) {
        int n = c0g + wc + ng*16 + ln;
        if (n < NY) {
            float bias = bh[n];
            #pragma unroll
            for (int rg = 0; rg < 4; ++rg) {
                int row = r0g + wr + rg*16 + kq*4;
                #pragma unroll
                for (int r = 0; r < 4; ++r)
                    Y[(size_t)(row + r) * NY + n] = acc[rg][ng][r] + bias;
            }
        }
    }
}

extern "C" void kernel_launch(void* const* d_in, const int* in_sizes, int n_in,
                              void* d_out, int out_size, void* d_ws, size_t ws_size,
                              hipStream_t stream) {
    const float* X        = (const float*)d_in[0];   // [8192,768]
    const float* clusters = (const float*)d_in[1];   // [500,100,768]
    const float* C        = (const float*)d_in[2];   // [768,64]
    const float* W        = (const float*)d_in[3];   // [768,1000]
    const float* bh       = (const float*)d_in[4];   // [1000]
    float* out = (float*)d_out;                      // y_pred, L1, L2
    float* ws  = (float*)d_ws;

    float* gramP = ws;                    // 4 x 4096 = 16384
    float* ginv  = gramP + 16384;         // 4096
    float* Up    = ginv  + 4096;          // 4 x 64000 = 256000
    float* SP    = Up    + 256000;        // 25 x 32768 = 819200 (score partials)
    float* Sfin  = SP    + 819200;        // 32768 (500x64 used)
    float* TbF   = Sfin  + 32768;         // 262144 floats (Tb bf16)
    float* VbF   = TbF   + 262144;        // 32768 floats (Vb bf16)

    unsigned short* Tb  = (unsigned short*)TbF;
    unsigned short* Vb  = (unsigned short*)VbF;

    k_front <<<dim3(616), dim3(256), 0, stream>>>(clusters, C, W, X, gramP, Up, SP, Tb);
    k_mid   <<<dim3(9),   dim3(256), 0, stream>>>(gramP, SP, ginv, Sfin);
    k_vc    <<<dim3(17),  dim3(256), 0, stream>>>(ginv, Up, Sfin, Vb, out + (size_t)BS * NY);
    k_ypred <<<dim3(512), dim3(256), 0, stream>>>((const uint4*)Tb, (const uint4*)Vb, bh, out);
}